// Round 3
// baseline (539.149 us; speedup 1.0000x reference)
//
#include <hip/hip_runtime.h>
#include <hip/hip_bf16.h>
#include <stdint.h>

#define B_  4096
#define IN_ 1024
#define H_  2048
#define K_  (IN_ + H_)   // 3072
#define N_  (5 * H_)     // 10240

// GEMM geometry: 256-row tile x (32 cols/gate x 5 gates), BK=64, 8 waves.
#define BM2 256
#define BJ2 32
#define BK2 64
#define NT2 48           // K_/BK2

typedef __attribute__((ext_vector_type(8))) short   short8;
typedef __attribute__((ext_vector_type(4))) float   f32x4;
typedef __attribute__((ext_vector_type(8))) unsigned short ushort8;

// ---------- helpers ----------
__device__ __forceinline__ unsigned short f2bf(float f) {
  union { float f; unsigned u; } cv; cv.f = f;
  unsigned u = cv.u;
  u += 0x7fffu + ((u >> 16) & 1u);   // round-to-nearest-even
  return (unsigned short)(u >> 16);
}

__device__ __forceinline__ void async16(const unsigned short* g, unsigned short* l) {
  __builtin_amdgcn_global_load_lds(
      (const __attribute__((address_space(1))) unsigned int*)g,
      (__attribute__((address_space(3))) unsigned int*)(void*)l,
      16, 0, 0);
}

__device__ __forceinline__ float fsig(float x) {
  return __builtin_amdgcn_rcpf(1.f + __expf(-x));   // rcp(inf)=0 -> safe
}
__device__ __forceinline__ float ftanh(float x) {
  return 1.f - 2.f * __builtin_amdgcn_rcpf(__expf(2.f * x) + 1.f);
}

// ---------- kernel 1: combined = bf16([x | h_prev])  [B_, K_] ----------
__global__ void build_combined(const float* __restrict__ x,
                               const float* __restrict__ h,
                               unsigned short* __restrict__ out) {
  const int row = blockIdx.x;
  const float4* xr = (const float4*)(x + (size_t)row * IN_);
  const float4* hr = (const float4*)(h + (size_t)row * H_);
  uint2* orow = (uint2*)(out + (size_t)row * K_);
  for (int c = threadIdx.x; c < K_ / 4; c += 256) {
    float4 v = (c < IN_ / 4) ? xr[c] : hr[c - IN_ / 4];
    uint2 p;
    p.x = (unsigned)f2bf(v.x) | ((unsigned)f2bf(v.y) << 16);
    p.y = (unsigned)f2bf(v.z) | ((unsigned)f2bf(v.w) << 16);
    orow[c] = p;
  }
}

// ---------- kernel 2: Wt[n][k] = bf16(W[k][n])  (64x64 LDS-tiled) ----------
__global__ __launch_bounds__(256) void transpose_convert(
    const float* __restrict__ W, unsigned short* __restrict__ Wt) {
  __shared__ float tile[64][65];
  const int n0 = blockIdx.x * 64;          // 160 blocks
  const int k0 = blockIdx.y * 64;          // 48 blocks
  const int t  = threadIdx.x;

  const int r0 = t >> 4;                   // 0..15
  const int c4 = t & 15;                   // float4 col index
  #pragma unroll
  for (int i = 0; i < 4; ++i) {
    const int kk = i * 16 + r0;
    const float4 v = *(const float4*)&W[(size_t)(k0 + kk) * N_ + n0 + c4 * 4];
    float* dst = &tile[kk][c4 * 4];
    dst[0] = v.x; dst[1] = v.y; dst[2] = v.z; dst[3] = v.w;
  }
  __syncthreads();

  #pragma unroll
  for (int i = 0; i < 2; ++i) {
    const int c2 = t + i * 256;
    const int nn = c2 >> 3;
    const int kc = (c2 & 7) * 8;
    ushort8 p;
    #pragma unroll
    for (int u = 0; u < 8; ++u) p[u] = f2bf(tile[kc + u][nn]);
    *(ushort8*)&Wt[(size_t)(n0 + nn) * K_ + k0 + kc] = p;
  }
}

// ---------- kernel 3: fused GEMM + xLSTM gate epilogue ----------
// 256-row / 8-wave / BK=64 phase-interleaved schedule (T2+T3+T4+T5 stack):
//   - per K-tile: 2 phases (k-sub 0 / k-sub 1), each {stage-issue | 9x
//     ds_read_b128 -> barrier -> lgkmcnt(0) -> setprio(1)+20 MFMA -> barrier}
//   - counted s_waitcnt vmcnt(4) once per K-tile (retires tile-t loads,
//     keeps the 4 just-issued A-stages in flight); vmcnt(0) only at t=47
//   - 128B-row XOR swizzle: stage src k-slot (lane&7)^(lane>>3), read slot
//     (ks*4+quad)^(lr&7) -> <=2-way bank aliasing (free)
//   - LDS 104KB dbuf -> 1 block/CU, 8 waves (2/SIMD), like the m201 template
__global__ __launch_bounds__(512, 2) void gemm_fused(
    const unsigned short* __restrict__ A,   // [B_, K_] bf16
    const unsigned short* __restrict__ Bt,  // [N_, K_] bf16
    const float* __restrict__ c_prev,       // [B_, H_]
    const float* __restrict__ bias,         // [5*H_]
    float* __restrict__ out)                // ht | ct
{
  __shared__ unsigned short As[2][BM2 * BK2];       // 2 x 32 KB
  __shared__ unsigned short Bs[2][5 * BJ2 * BK2];   // 2 x 20 KB

  const int tid  = threadIdx.x;
  const int wave = tid >> 6;        // 0..7
  const int lane = tid & 63;
  const int quad = lane >> 4;
  const int lr   = lane & 15;

  const int tile_m = blockIdx.x >> 6;     // 16 m-tiles
  const int tile_j = blockIdx.x & 63;     // 64 j-tiles
  const int m0 = tile_m * BM2;
  const int j0 = tile_j * BJ2;

  const int wm = (wave & 3) * 64;         // row quarter (4 m-frags each)
  const int wn = (wave >> 2) * 16;        // col half within the 32-col j-tile

  f32x4 acc[4][5];
  #pragma unroll
  for (int mi = 0; mi < 4; ++mi)
    #pragma unroll
    for (int g = 0; g < 5; ++g)
      acc[mi][g] = (f32x4){0.f, 0.f, 0.f, 0.f};

  // ---- staging addressing: chunk = 8 rows x 128B; lane: row=lane>>3,
  // phys slot=lane&7; source fetches logical k-slot (slot ^ row) so the
  // swizzle is an involution shared with the read side (rule 21).
  const int lrow8 = lane >> 3;                       // 0..7
  const int sw8   = ((lane & 7) ^ lrow8) * 8;        // shorts

  // A: wave stages chunks {w, w+8, w+16, w+24} (rows 8c..8c+7)
  const unsigned short* aSrc =
      A + (size_t)(m0 + 8 * wave + lrow8) * K_ + sw8;

  // B-tile rows: r = gate*32 + jcol; chunk c -> gate c>>2, jcol (c&3)*8+row
  const bool doTail = (wave < 4);                    // 3rd B chunk
  const int cB0 = wave;
  const int cB1 = wave + 8;
  const int cB2 = doTail ? wave + 16 : wave;         // clamped if unused
  const unsigned short* bSrc0 =
      Bt + (size_t)((cB0 >> 2) * H_ + j0 + (cB0 & 3) * 8 + lrow8) * K_ + sw8;
  const unsigned short* bSrc1 =
      Bt + (size_t)((cB1 >> 2) * H_ + j0 + (cB1 & 3) * 8 + lrow8) * K_ + sw8;
  const unsigned short* bSrc2 =
      Bt + (size_t)((cB2 >> 2) * H_ + j0 + (cB2 & 3) * 8 + lrow8) * K_ + sw8;

  #define STAGE_A(ko_, bb) do {                                        \
    async16(aSrc + (ko_),                    &As[bb][512 * wave]);     \
    async16(aSrc + (size_t) 64 * K_ + (ko_), &As[bb][512 * (wave + 8)]);  \
    async16(aSrc + (size_t)128 * K_ + (ko_), &As[bb][512 * (wave + 16)]); \
    async16(aSrc + (size_t)192 * K_ + (ko_), &As[bb][512 * (wave + 24)]); \
  } while (0)
  #define STAGE_B(ko_, bb) do {                                        \
    async16(bSrc0 + (ko_), &Bs[bb][512 * cB0]);                        \
    async16(bSrc1 + (ko_), &Bs[bb][512 * cB1]);                        \
    if (doTail) async16(bSrc2 + (ko_), &Bs[bb][512 * cB2]);            \
  } while (0)

  // prologue: tile 0 fully issued into buffer 0
  STAGE_A((size_t)0, 0);
  STAGE_B((size_t)0, 0);

  // fragment read slots (shorts): logical slot q=ks*4+quad, phys q^(lr&7)
  const int rs0 = ((0 + quad) ^ (lr & 7)) * 8;
  const int rs1 = ((4 + quad) ^ (lr & 7)) * 8;
  const int aR[4] = { (wm + 0 * 16 + lr) * BK2, (wm + 1 * 16 + lr) * BK2,
                      (wm + 2 * 16 + lr) * BK2, (wm + 3 * 16 + lr) * BK2 };
  const int bR[5] = { (0 * 32 + wn + lr) * BK2, (1 * 32 + wn + lr) * BK2,
                      (2 * 32 + wn + lr) * BK2, (3 * 32 + wn + lr) * BK2,
                      (4 * 32 + wn + lr) * BK2 };

  #pragma unroll 2
  for (int t = 0; t < NT2; ++t) {
    const int cur = t & 1;
    const size_t koN = (size_t)(t + 1) * BK2;

    // ======== phase 0 (k-sub 0) ========
    if (t < NT2 - 1) STAGE_A(koN, cur ^ 1);
    // counted wait: retire tile t's 6|7 loads; the 4 A-stages just issued
    // (and phase-1's B-stages) stay in flight. Never 0 in the main loop.
    if (t == NT2 - 1) asm volatile("s_waitcnt vmcnt(0)" ::: "memory");
    else              asm volatile("s_waitcnt vmcnt(4)" ::: "memory");
    __builtin_amdgcn_s_barrier();          // all waves' tile-t data resident

    short8 af0[4], bf0[5];
    #pragma unroll
    for (int mi = 0; mi < 4; ++mi)
      af0[mi] = *(const short8*)&As[cur][aR[mi] + rs0];
    #pragma unroll
    for (int g = 0; g < 5; ++g)
      bf0[g] = *(const short8*)&Bs[cur][bR[g] + rs0];
    asm volatile("s_waitcnt lgkmcnt(0)" ::: "memory");
    __builtin_amdgcn_sched_barrier(0);

    __builtin_amdgcn_s_setprio(1);
    #pragma unroll
    for (int mi = 0; mi < 4; ++mi)
      #pragma unroll
      for (int g = 0; g < 5; ++g)
        acc[mi][g] = __builtin_amdgcn_mfma_f32_16x16x32_bf16(
            af0[mi], bf0[g], acc[mi][g], 0, 0, 0);
    __builtin_amdgcn_s_setprio(0);
    __builtin_amdgcn_s_barrier();

    // ======== phase 1 (k-sub 1) ========
    if (t < NT2 - 1) STAGE_B(koN, cur ^ 1);
    short8 af1[4], bf1[5];
    #pragma unroll
    for (int mi = 0; mi < 4; ++mi)
      af1[mi] = *(const short8*)&As[cur][aR[mi] + rs1];
    #pragma unroll
    for (int g = 0; g < 5; ++g)
      bf1[g] = *(const short8*)&Bs[cur][bR[g] + rs1];
    __builtin_amdgcn_s_barrier();          // read-latency overlaps the wait
    asm volatile("s_waitcnt lgkmcnt(0)" ::: "memory");
    __builtin_amdgcn_sched_barrier(0);

    __builtin_amdgcn_s_setprio(1);
    #pragma unroll
    for (int mi = 0; mi < 4; ++mi)
      #pragma unroll
      for (int g = 0; g < 5; ++g)
        acc[mi][g] = __builtin_amdgcn_mfma_f32_16x16x32_bf16(
            af1[mi], bf1[g], acc[mi][g], 0, 0, 0);
    __builtin_amdgcn_s_setprio(0);
    __builtin_amdgcn_s_barrier();
  }
  #undef STAGE_A
  #undef STAGE_B

  // ---- fused epilogue: all 5 gates in-lane, fp32 throughout ----
  const int col = j0 + wn + lr;                    // 0..H_-1
  float bb[5];
  #pragma unroll
  for (int g = 0; g < 5; ++g) bb[g] = bias[g * H_ + col];

  #pragma unroll
  for (int mi = 0; mi < 4; ++mi) {
    const int rbase = m0 + wm + mi * 16 + quad * 4;
    float cp[4];
    #pragma unroll
    for (int r = 0; r < 4; ++r)
      cp[r] = c_prev[(size_t)(rbase + r) * H_ + col];
    #pragma unroll
    for (int r = 0; r < 4; ++r) {
      const float ft = fsig(acc[mi][0][r] + bb[0]);
      const float it = fsig(acc[mi][1][r] + bb[1]);
      const float ch = ftanh(acc[mi][2][r] + bb[2]);
      const float ot = fsig(acc[mi][3][r] + bb[3]);
      const float et = fsig(acc[mi][4][r] + bb[4]);
      const float ct = ft * cp[r] + it * ch;
      const float th = ftanh(ct);
      float ht = ot * th;
      ht = et * __expf(ht) + (1.f - et) * ht;
      out[(size_t)(rbase + r) * H_ + col] = ht;
      out[(size_t)B_ * H_ + (size_t)(rbase + r) * H_ + col] = ct;
    }
  }
}

// ---------- launcher ----------
extern "C" void kernel_launch(void* const* d_in, const int* in_sizes, int n_in,
                              void* d_out, int out_size, void* d_ws, size_t ws_size,
                              hipStream_t stream) {
  const float* x = (const float*)d_in[0];
  const float* h = (const float*)d_in[1];
  const float* c = (const float*)d_in[2];
  const float* W = (const float*)d_in[3];
  const float* b = (const float*)d_in[4];
  float* out = (float*)d_out;

  char* ws = (char*)d_ws;
  unsigned short* combined = (unsigned short*)ws;                  // 24 MB
  unsigned short* Wt = (unsigned short*)(ws + (size_t)25165824);   // 60 MB

  build_combined<<<B_, 256, 0, stream>>>(x, h, combined);
  transpose_convert<<<dim3(N_ / 64, K_ / 64), 256, 0, stream>>>(W, Wt);
  gemm_fused<<<(B_ / BM2) * (H_ / BJ2), 512, 0, stream>>>(combined, Wt, c, b, out);
}